// Round 14
// baseline (89.252 us; speedup 1.0000x reference)
//
#include <hip/hip_runtime.h>

#define NN 50000
#define NE 800000
#define DD 96
#define NEG 0.01f
#define FN 64        // nodes per fuse4 block
#define XST 104      // LDS row stride (bf16 units)
#define NBK 196      // buckets = row>>8 (256 rows each)
#define BCAP 4600    // bucket region capacity (mean 4096, sigma 64; overflow exact)
#define EPA 4096     // edges per binA block
#define NBA 196      // binA blocks
#define OVCAP 65536  // overflow list capacity (normally 0 used)
#define QROW 128     // egoq row stride BYTES: [96 int8][f32 scale][pad]

typedef __attribute__((ext_vector_type(8))) short short8v;
typedef __attribute__((ext_vector_type(4))) float f32x4;

static __device__ __forceinline__ float lrelu(float x) {
  return (x >= 0.f) ? x : NEG * x;
}
static __device__ __forceinline__ unsigned short f2bf(float x) {
  unsigned u = __float_as_uint(x);
  u += 0x7fffu + ((u >> 16) & 1u);   // RNE
  return (unsigned short)(u >> 16);
}
static __device__ __forceinline__ float bf2f(unsigned short h) {
  return __uint_as_float(((unsigned)h) << 16);
}
static __device__ __forceinline__ float bflo(unsigned u) {
  return __uint_as_float(u << 16);
}
static __device__ __forceinline__ float bfhi(unsigned u) {
  return __uint_as_float(u & 0xFFFF0000u);
}
static __device__ __forceinline__ float sb(unsigned u, int k) {  // signed byte k -> f32
  return (float)((int)(signed char)((u >> (8 * k)) & 0xFF));
}

// ================= fallback (round-1) path =================
__global__ __launch_bounds__(256) void scatter_kernel(
    const float* __restrict__ ego, const float* __restrict__ avals,
    const int* __restrict__ arows, const int* __restrict__ acols,
    float* __restrict__ side)
{
  int t = blockIdx.x * 256 + threadIdx.x;
  int e = t >> 5;
  int lane = t & 31;
  if (e >= NE) return;
  int row = arows[e];
  int col = acols[e];
  float v = avals[e];
  if (lane < 24) {
    const float4* src = (const float4*)(ego + (size_t)col * DD);
    float4 x = src[lane];
    float* dst = side + (size_t)row * DD + lane * 4;
    unsafeAtomicAdd(dst + 0, v * x.x);
    unsafeAtomicAdd(dst + 1, v * x.y);
    unsafeAtomicAdd(dst + 2, v * x.z);
    unsafeAtomicAdd(dst + 3, v * x.w);
  }
}

__global__ __launch_bounds__(192) void fuse_fb_kernel(
    const float* __restrict__ ego, const float* __restrict__ side,
    const float* __restrict__ W1, const float* __restrict__ b1,
    const float* __restrict__ W2, const float* __restrict__ b2,
    float* __restrict__ out)
{
  __shared__ float W1t[DD * DD];
  __shared__ float W2t[DD * DD];
  __shared__ float b1s[DD], b2s[DD];
  __shared__ float xs[192], ys[192];
  int tid = threadIdx.x;
  for (int i = tid; i < DD * DD; i += 192) {
    int j = i / DD, k = i - j * DD;
    W1t[k * DD + j] = W1[i];
    W2t[k * DD + j] = W2[i];
  }
  if (tid < DD) { b1s[tid] = b1[tid]; b2s[tid] = b2[tid]; }
  __syncthreads();
  int nl = tid / DD, j = tid - nl * DD;
  for (int p = blockIdx.x; p < NN / 2; p += gridDim.x) {
    int base = p * 192;
    float e = ego[base + tid], s = side[base + tid];
    xs[tid] = e + s; ys[tid] = e * s;
    __syncthreads();
    float a1 = b1s[j], a2 = b2s[j];
    const float* xr = xs + nl * DD;
    const float* yr = ys + nl * DD;
#pragma unroll 16
    for (int k = 0; k < DD; ++k) {
      a1 += xr[k] * W1t[k * DD + j];
      a2 += yr[k] * W2t[k * DD + j];
    }
    float r = lrelu(a1) + lrelu(a2);
    __syncthreads();
    out[base + tid] = r;
  }
}

// ========== build: binA binning + W->bf16 + ego->int8(row-scale) ==========
#define NB_W   ((DD * DD) / 256)       // 36
#define NB_Q   ((NN + 63) / 64)        // 782 quant blocks (64 rows each)
__global__ __launch_bounds__(256) void build_kernel(
    const int* __restrict__ rows, const int* __restrict__ cols,
    const float* __restrict__ vals,
    int* __restrict__ bptr, int* __restrict__ ovcur,
    int2* __restrict__ ovbuf, int2* __restrict__ buckets,
    const float* __restrict__ W1, const float* __restrict__ W2,
    unsigned short* __restrict__ Wb1, unsigned short* __restrict__ Wb2,
    const float* __restrict__ ego, unsigned char* __restrict__ egoq)
{
  __shared__ unsigned sw0[EPA];
  __shared__ unsigned sw1[EPA];
  __shared__ unsigned char sbid[EPA];
  __shared__ int bcnt[256], bofs[256], gbase[256], stmp[256];

  int blk = blockIdx.x;
  int tid = threadIdx.x;

  if (blk >= NBA) {
    int b = blk - NBA;
    if (b < NB_W) {
      int i = b * 256 + tid;  // [0, 9216)
      Wb1[i] = f2bf(W1[i]);
      Wb2[i] = f2bf(W2[i]);
    } else {
      // int8 quantization: 64 rows/block, 4 threads/row (24 values each)
      int r_loc = tid >> 2, q = tid & 3;
      int row = (b - NB_W) * 64 + r_loc;
      if (row < NN) {
        float4 f[6];
        const float4* src = (const float4*)(ego + (size_t)row * DD + q * 24);
#pragma unroll
        for (int t = 0; t < 6; ++t) f[t] = src[t];
        float m = 0.f;
#pragma unroll
        for (int t = 0; t < 6; ++t) {
          m = fmaxf(m, fmaxf(fmaxf(fabsf(f[t].x), fabsf(f[t].y)),
                             fmaxf(fabsf(f[t].z), fabsf(f[t].w))));
        }
        m = fmaxf(m, __shfl_xor(m, 1, 64));
        m = fmaxf(m, __shfl_xor(m, 2, 64));
        m = fmaxf(m, 1e-20f);
        float inv = 127.0f / m;
        unsigned* dst = (unsigned*)(egoq + (size_t)row * QROW) + q * 6;
#pragma unroll
        for (int t = 0; t < 6; ++t) {
          int q0 = __float2int_rn(f[t].x * inv);
          int q1 = __float2int_rn(f[t].y * inv);
          int q2 = __float2int_rn(f[t].z * inv);
          int q3 = __float2int_rn(f[t].w * inv);
          dst[t] = (unsigned)(q0 & 255) | ((unsigned)(q1 & 255) << 8) |
                   ((unsigned)(q2 & 255) << 16) | ((unsigned)(q3 & 255) << 24);
        }
        if (q == 0) *(float*)(egoq + (size_t)row * QROW + DD) = m * (1.0f / 127.0f);
      }
    }
    return;
  }

  // ---- binA part ----
  int base = blk * EPA;
  int cnt_here = min(EPA, NE - base);

  bcnt[tid] = 0;
  __syncthreads();

  unsigned w0[16], w1[16];
  int bb[16], lp[16];
#pragma unroll
  for (int k = 0; k < 16; ++k) {
    int i = tid + k * 256;
    bb[k] = -1;
    if (i < cnt_here) {
      int e = base + i;
      int r = rows[e], c = cols[e];
      float v = vals[e];
      int b = r >> 8;
      bb[k] = b;
      w0[k] = (unsigned)c | ((unsigned)(r & 255) << 16) | ((unsigned)b << 24);
      w1[k] = (unsigned)f2bf(v);
      lp[k] = atomicAdd(&bcnt[b], 1);
    }
  }
  __syncthreads();

  int v = bcnt[tid];
  stmp[tid] = v;
  __syncthreads();
  for (int off = 1; off < 256; off <<= 1) {
    int add = (tid >= off) ? stmp[tid - off] : 0;
    __syncthreads();
    stmp[tid] += add;
    __syncthreads();
  }
  bofs[tid] = stmp[tid] - v;  // exclusive
  gbase[tid] = (tid < NBK && v > 0) ? atomicAdd(&bptr[tid], v) : 0;
  __syncthreads();

#pragma unroll
  for (int k = 0; k < 16; ++k) {
    if (bb[k] >= 0) {
      int s = bofs[bb[k]] + lp[k];
      sw0[s] = w0[k];
      sw1[s] = w1[k];
      sbid[s] = (unsigned char)bb[k];
    }
  }
  __syncthreads();

  for (int i = tid; i < cnt_here; i += 256) {
    int b = sbid[i];
    int off = i - bofs[b];
    int g = gbase[b] + off;
    int2 ent = make_int2((int)sw0[i], (int)sw1[i]);
    if (g < BCAP) {
      buckets[(size_t)b * BCAP + g] = ent;
    } else {
      int op = atomicAdd(ovcur, 1);
      if (op < OVCAP) ovbuf[op] = ent;
    }
  }
}

// ========== binB: LDS-staged bucket + counting sort -> cv + row_start ==========
__global__ __launch_bounds__(256) void binB_kernel(
    const int2* __restrict__ buckets, const int* __restrict__ bptr,
    const int* __restrict__ ovcur, const int2* __restrict__ ovbuf,
    unsigned* __restrict__ cv, int* __restrict__ row_start)
{
  __shared__ int2 sent[BCAP];
  __shared__ int rcnt[256], rofs[256], rcur[256], stmp[256], sexc[256];
  int b = blockIdx.x, tid = threadIdx.x;

  int bv = (tid < NBK) ? bptr[tid] : 0;
  stmp[tid] = bv;
  __syncthreads();
  for (int off = 1; off < 256; off <<= 1) {
    int add = (tid >= off) ? stmp[tid - off] : 0;
    __syncthreads();
    stmp[tid] += add;
    __syncthreads();
  }
  sexc[tid] = stmp[tid] - bv;
  __syncthreads();
  int cvb = sexc[b];
  int total = bptr[b];
  int nreg = min(total, BCAP);
  int nov = min(*ovcur, OVCAP);
  const int2* reg = buckets + (size_t)b * BCAP;

  rcnt[tid] = 0;
  for (int i = tid; i < nreg; i += 256) sent[i] = reg[i];
  __syncthreads();

  for (int i = tid; i < nreg; i += 256) {
    unsigned w0 = (unsigned)sent[i].x;
    atomicAdd(&rcnt[(w0 >> 16) & 255], 1);
  }
  for (int i = tid; i < nov; i += 256) {
    unsigned w0 = (unsigned)ovbuf[i].x;
    if ((w0 >> 24) == (unsigned)b) atomicAdd(&rcnt[(w0 >> 16) & 255], 1);
  }
  __syncthreads();

  int v = rcnt[tid];
  stmp[tid] = v;
  __syncthreads();
  for (int off = 1; off < 256; off <<= 1) {
    int add = (tid >= off) ? stmp[tid - off] : 0;
    __syncthreads();
    stmp[tid] += add;
    __syncthreads();
  }
  rofs[tid] = stmp[tid] - v;
  rcur[tid] = rofs[tid];
  int grow = b * 256 + tid;
  if (grow <= NN) row_start[grow] = cvb + rofs[tid];
  __syncthreads();

  for (int i = tid; i < nreg; i += 256) {
    unsigned w0 = (unsigned)sent[i].x;
    unsigned w1 = (unsigned)sent[i].y;
    int rl = (w0 >> 16) & 255;
    int p = atomicAdd(&rcur[rl], 1);
    cv[cvb + p] = (w0 & 0xFFFFu) | (w1 << 16);
  }
  for (int i = tid; i < nov; i += 256) {
    unsigned w0 = (unsigned)ovbuf[i].x;
    unsigned w1 = (unsigned)ovbuf[i].y;
    if ((w0 >> 24) == (unsigned)b) {
      int rl = (w0 >> 16) & 255;
      int p = atomicAdd(&rcur[rl], 1);
      cv[cvb + p] = (w0 & 0xFFFFu) | (w1 << 16);
    }
  }
}

// ====== agg: DUAL-ROW per wave, quarter-wave gathers, 3-phase pipeline ======
// Wave owns rows r0=blk*8+wid*2, r1=r0+1. Per 16-slot batch both rows'
// broadcasts, loads, and FMAs are grouped -> 16 uint2 gathers in flight/lane.
__global__ __launch_bounds__(256) void agg_kernel(
    const unsigned char* __restrict__ egoq, const int* __restrict__ row_start,
    const unsigned* __restrict__ cv, unsigned* __restrict__ sideb) {
  int wid = threadIdx.x >> 6, lane = threadIdx.x & 63;
  int r0 = blockIdx.x * 8 + wid * 2;
  if (r0 >= NN) return;
  int r1 = r0 + 1;
  bool has1 = r1 < NN;
  int s0 = row_start[r0], e0 = row_start[r0 + 1];
  int s1 = has1 ? row_start[r1] : 0;
  int e1 = has1 ? row_start[r1 + 1] : 0;
  int q = lane >> 4, ql = lane & 15;
  bool act = ql < 12;
  int ql8 = ql * 8;

  float a0[4][8], a1[4][8];
#pragma unroll
  for (int d = 0; d < 4; ++d)
#pragma unroll
    for (int j = 0; j < 8; ++j) { a0[d][j] = 0.f; a1[d][j] = 0.f; }

  int len0 = e0 - s0, len1 = e1 - s1;
  int nblk = max((len0 + 63) >> 6, (len1 + 63) >> 6);

  for (int blk = 0; blk < nblk; ++blk) {
    int base0 = s0 + blk * 64, base1 = s1 + blk * 64;
    unsigned pk0 = 0, pk1 = 0;
    if (base0 + lane < e0) pk0 = cv[base0 + lane];
    if (has1 && base1 + lane < e1) pk1 = cv[base1 + lane];
    int n0 = min(64, max(0, e0 - base0));
    int n1 = min(64, max(0, e1 - base1));
    int n = max(n0, n1);
    for (int i = 0; i < n; i += 16) {
      bool go0 = i < n0, go1 = i < n1;
      // phase 1: broadcasts for both rows
      unsigned p0[4], p1[4];
#pragma unroll
      for (int d = 0; d < 4; ++d) {
        p0[d] = __shfl(pk0, i + 4 * d + q, 64);
        p1[d] = __shfl(pk1, i + 4 * d + q, 64);
      }
      // phase 2: issue all loads (up to 16 gathers + 16 scale loads in flight)
      uint2 u0[4], u1[4];
      float sc0[4], sc1[4];
#pragma unroll
      for (int d = 0; d < 4; ++d) {
        const char* rp0 = (const char*)egoq + ((size_t)(p0[d] & 0xFFFFu) << 7);
        const char* rp1 = (const char*)egoq + ((size_t)(p1[d] & 0xFFFFu) << 7);
        if (act && go0) {
          u0[d] = *(const uint2*)(rp0 + ql8);
          sc0[d] = *(const float*)(rp0 + DD);
        } else { u0[d] = make_uint2(0u, 0u); sc0[d] = 0.f; }
        if (act && go1) {
          u1[d] = *(const uint2*)(rp1 + ql8);
          sc1[d] = *(const float*)(rp1 + DD);
        } else { u1[d] = make_uint2(0u, 0u); sc1[d] = 0.f; }
      }
      // phase 3: fma everything
#pragma unroll
      for (int d = 0; d < 4; ++d) {
        float vs0 = bfhi(p0[d]) * sc0[d];
        float vs1 = bfhi(p1[d]) * sc1[d];
        a0[d][0] += vs0 * sb(u0[d].x, 0); a1[d][0] += vs1 * sb(u1[d].x, 0);
        a0[d][1] += vs0 * sb(u0[d].x, 1); a1[d][1] += vs1 * sb(u1[d].x, 1);
        a0[d][2] += vs0 * sb(u0[d].x, 2); a1[d][2] += vs1 * sb(u1[d].x, 2);
        a0[d][3] += vs0 * sb(u0[d].x, 3); a1[d][3] += vs1 * sb(u1[d].x, 3);
        a0[d][4] += vs0 * sb(u0[d].y, 0); a1[d][4] += vs1 * sb(u1[d].y, 0);
        a0[d][5] += vs0 * sb(u0[d].y, 1); a1[d][5] += vs1 * sb(u1[d].y, 1);
        a0[d][6] += vs0 * sb(u0[d].y, 2); a1[d][6] += vs1 * sb(u1[d].y, 2);
        a0[d][7] += vs0 * sb(u0[d].y, 3); a1[d][7] += vs1 * sb(u1[d].y, 3);
      }
    }
  }

  float v0[8], v1[8];
#pragma unroll
  for (int j = 0; j < 8; ++j) {
    v0[j] = (a0[0][j] + a0[1][j]) + (a0[2][j] + a0[3][j]);
    v0[j] += __shfl_xor(v0[j], 16, 64);
    v0[j] += __shfl_xor(v0[j], 32, 64);
    v1[j] = (a1[0][j] + a1[1][j]) + (a1[2][j] + a1[3][j]);
    v1[j] += __shfl_xor(v1[j], 16, 64);
    v1[j] += __shfl_xor(v1[j], 32, 64);
  }
  if (q == 0 && act) {
    uint4 o;
    o.x = (unsigned)f2bf(v0[0]) | ((unsigned)f2bf(v0[1]) << 16);
    o.y = (unsigned)f2bf(v0[2]) | ((unsigned)f2bf(v0[3]) << 16);
    o.z = (unsigned)f2bf(v0[4]) | ((unsigned)f2bf(v0[5]) << 16);
    o.w = (unsigned)f2bf(v0[6]) | ((unsigned)f2bf(v0[7]) << 16);
    *(uint4*)(sideb + (size_t)r0 * 48 + ql * 4) = o;
  }
  if (q == 1 && act && has1) {
    uint4 o;
    o.x = (unsigned)f2bf(v1[0]) | ((unsigned)f2bf(v1[1]) << 16);
    o.y = (unsigned)f2bf(v1[2]) | ((unsigned)f2bf(v1[3]) << 16);
    o.z = (unsigned)f2bf(v1[4]) | ((unsigned)f2bf(v1[5]) << 16);
    o.w = (unsigned)f2bf(v1[6]) | ((unsigned)f2bf(v1[7]) << 16);
    *(uint4*)(sideb + (size_t)r1 * 48 + ql * 4) = o;
  }
}

// ========== fuse4: bf16 MFMA, staged from egoq(int8)+sideb(bf16) ==========
__global__ __launch_bounds__(256) void fuse4_kernel(
    const unsigned char* __restrict__ egoq, const unsigned* __restrict__ sideb,
    const unsigned short* __restrict__ Wb1, const unsigned short* __restrict__ Wb2,
    const float* __restrict__ b1, const float* __restrict__ b2,
    float* __restrict__ out)
{
  __shared__ unsigned short xs[FN * XST];
  __shared__ unsigned short ys[FN * XST];
  int tid = threadIdx.x;
  int nbase = blockIdx.x * FN;

  // stage x=e+s, y=e*s as bf16; FN*24 dword units, 6 iters/thread
  for (int i = tid; i < FN * 24; i += 256) {
    int r = i / 24, u = i - r * 24;
    float e0 = 0.f, e1 = 0.f, e2 = 0.f, e3 = 0.f;
    float s0 = 0.f, s1 = 0.f, s2 = 0.f, s3 = 0.f;
    if (nbase + r < NN) {
      const char* rowp = (const char*)egoq + ((size_t)(nbase + r) << 7);
      float sc = *(const float*)(rowp + DD);
      unsigned uq = *(const unsigned*)(rowp + u * 4);
      e0 = sc * sb(uq, 0);
      e1 = sc * sb(uq, 1);
      e2 = sc * sb(uq, 2);
      e3 = sc * sb(uq, 3);
      uint2 sv = *(const uint2*)(sideb + (size_t)(nbase + r) * 48 + u * 2);
      s0 = bflo(sv.x); s1 = bfhi(sv.x);
      s2 = bflo(sv.y); s3 = bfhi(sv.y);
    }
    unsigned xlo = (unsigned)f2bf(e0 + s0) | ((unsigned)f2bf(e1 + s1) << 16);
    unsigned xhi = (unsigned)f2bf(e2 + s2) | ((unsigned)f2bf(e3 + s3) << 16);
    unsigned ylo = (unsigned)f2bf(e0 * s0) | ((unsigned)f2bf(e1 * s1) << 16);
    unsigned yhi = (unsigned)f2bf(e2 * s2) | ((unsigned)f2bf(e3 * s3) << 16);
    *(uint2*)(xs + r * XST + u * 4) = make_uint2(xlo, xhi);
    *(uint2*)(ys + r * XST + u * 4) = make_uint2(ylo, yhi);
  }
  __syncthreads();

  int w = tid >> 6, l = tid & 63;
  int lrow = l & 15, lk = l >> 4;

  f32x4 acc1[6], acc2[6];
#pragma unroll
  for (int t = 0; t < 6; ++t) {
    acc1[t] = (f32x4){0.f, 0.f, 0.f, 0.f};
    acc2[t] = (f32x4){0.f, 0.f, 0.f, 0.f};
  }

  const unsigned short* xrow = xs + (w * 16 + lrow) * XST + lk * 8;
  const unsigned short* yrow = ys + (w * 16 + lrow) * XST + lk * 8;

#pragma unroll
  for (int kk = 0; kk < 3; ++kk) {
    short8v ax = *(const short8v*)(xrow + kk * 32);
    short8v ay = *(const short8v*)(yrow + kk * 32);
    int kb = kk * 32 + lk * 8;
#pragma unroll
    for (int t = 0; t < 6; ++t) {
      int j = t * 16 + lrow;
      short8v bw1 = *(const short8v*)(Wb1 + j * DD + kb);
      short8v bw2 = *(const short8v*)(Wb2 + j * DD + kb);
      acc1[t] = __builtin_amdgcn_mfma_f32_16x16x32_bf16(ax, bw1, acc1[t], 0, 0, 0);
      acc2[t] = __builtin_amdgcn_mfma_f32_16x16x32_bf16(ay, bw2, acc2[t], 0, 0, 0);
    }
  }

  int node0 = nbase + w * 16 + lk * 4;
#pragma unroll
  for (int t = 0; t < 6; ++t) {
    int j = t * 16 + lrow;
    float bb1 = b1[j], bb2 = b2[j];
#pragma unroll
    for (int i = 0; i < 4; ++i) {
      int node = node0 + i;
      if (node < NN)
        out[(size_t)node * DD + j] = lrelu(acc1[t][i] + bb1) + lrelu(acc2[t][i] + bb2);
    }
  }
}

// ================= launch =================
extern "C" void kernel_launch(void* const* d_in, const int* in_sizes, int n_in,
                              void* d_out, int out_size, void* d_ws, size_t ws_size,
                              hipStream_t stream) {
  const float* ego   = (const float*)d_in[0];
  const float* avals = (const float*)d_in[1];
  const float* W1    = (const float*)d_in[2];
  const float* b1    = (const float*)d_in[3];
  const float* W2    = (const float*)d_in[4];
  const float* b2    = (const float*)d_in[5];
  const int* arows   = (const int*)d_in[6];
  const int* acols   = (const int*)d_in[7];
  float* out = (float*)d_out;

  size_t off = 0;
  auto bump = [&](size_t bytes) {
    size_t o = off;
    off += (bytes + 1023) & ~(size_t)1023;
    return o;
  };
  char* ws = (char*)d_ws;
  size_t o_rs    = bump((size_t)(NN + 1) * 4);
  size_t o_cv    = bump((size_t)NE * 4);
  size_t o_wb1   = bump((size_t)DD * DD * 2);
  size_t o_wb2   = bump((size_t)DD * DD * 2);
  size_t o_egoq  = bump((size_t)NN * QROW);       // 6.4 MB int8 rows w/ scale
  size_t o_bptr  = bump((size_t)(NBK + 1) * 4);   // bptr[NBK] + ovcur
  size_t o_ovbuf = bump((size_t)OVCAP * 8);
  size_t o_sideb = bump((size_t)NN * DD * 2);     // 9.6 MB; buckets alias here
  size_t need = off;
  static_assert((size_t)NBK * BCAP * 8 <= (size_t)NN * DD * 2, "buckets fit in sideb");

  if (ws_size >= need) {
    int*  rs    = (int*)(ws + o_rs);
    unsigned* cv = (unsigned*)(ws + o_cv);
    unsigned short* Wb1  = (unsigned short*)(ws + o_wb1);
    unsigned short* Wb2  = (unsigned short*)(ws + o_wb2);
    unsigned char* egoq  = (unsigned char*)(ws + o_egoq);
    int*  bptr  = (int*)(ws + o_bptr);
    int*  ovcur = bptr + NBK;
    int2* ovbuf = (int2*)(ws + o_ovbuf);
    unsigned* sideb = (unsigned*)(ws + o_sideb);
    int2* buckets = (int2*)(ws + o_sideb);

    hipMemsetAsync(bptr, 0, (size_t)(NBK + 1) * 4, stream);
    build_kernel<<<NBA + NB_W + NB_Q, 256, 0, stream>>>(
        arows, acols, avals, bptr, ovcur, ovbuf, buckets,
        W1, W2, Wb1, Wb2, ego, egoq);
    binB_kernel<<<NBK, 256, 0, stream>>>(buckets, bptr, ovcur, ovbuf, cv, rs);
    agg_kernel<<<(NN + 7) / 8, 256, 0, stream>>>(egoq, rs, cv, sideb);
    fuse4_kernel<<<(NN + FN - 1) / FN, 256, 0, stream>>>(
        egoq, sideb, Wb1, Wb2, b1, b2, out);
  } else {
    size_t side_bytes = (size_t)NN * DD * sizeof(float);
    float* side = (ws_size >= side_bytes) ? (float*)d_ws : out;
    hipMemsetAsync(side, 0, side_bytes, stream);
    long long nthreads = (long long)NE * 32;
    int blocks = (int)((nthreads + 255) / 256);
    scatter_kernel<<<blocks, 256, 0, stream>>>(ego, avals, arows, acols, side);
    fuse_fb_kernel<<<1024, 192, 0, stream>>>(ego, side, W1, b1, W2, b2, out);
  }
}

// Round 15
// 83.482 us; speedup vs baseline: 1.0691x; 1.0691x over previous
//
#include <hip/hip_runtime.h>

#define NN 50000
#define NE 800000
#define DD 96
#define NEG 0.01f
#define FN 64        // nodes per fuse4 block
#define XST 104      // LDS row stride (bf16 units)
#define NBK 196      // buckets = row>>8 (256 rows each)
#define BCAP 4600    // bucket region capacity (mean 4096, sigma 64; overflow exact)
#define EPA 2048     // edges per binA block (halved from R12: more blocks, less LDS)
#define NBA ((NE + EPA - 1) / EPA)   // 391 binA blocks
#define OVCAP 65536  // overflow list capacity (normally 0 used)
#define QROW 128     // egoq row stride BYTES: [96 int8][f32 scale][pad]

typedef __attribute__((ext_vector_type(8))) short short8v;
typedef __attribute__((ext_vector_type(4))) float f32x4;

static __device__ __forceinline__ float lrelu(float x) {
  return (x >= 0.f) ? x : NEG * x;
}
static __device__ __forceinline__ unsigned short f2bf(float x) {
  unsigned u = __float_as_uint(x);
  u += 0x7fffu + ((u >> 16) & 1u);   // RNE
  return (unsigned short)(u >> 16);
}
static __device__ __forceinline__ float bf2f(unsigned short h) {
  return __uint_as_float(((unsigned)h) << 16);
}
static __device__ __forceinline__ float bflo(unsigned u) {
  return __uint_as_float(u << 16);
}
static __device__ __forceinline__ float bfhi(unsigned u) {
  return __uint_as_float(u & 0xFFFF0000u);
}
static __device__ __forceinline__ float sb(unsigned u, int k) {  // signed byte k -> f32
  return (float)((int)(signed char)((u >> (8 * k)) & 0xFF));
}

// ================= fallback (round-1) path =================
__global__ __launch_bounds__(256) void scatter_kernel(
    const float* __restrict__ ego, const float* __restrict__ avals,
    const int* __restrict__ arows, const int* __restrict__ acols,
    float* __restrict__ side)
{
  int t = blockIdx.x * 256 + threadIdx.x;
  int e = t >> 5;
  int lane = t & 31;
  if (e >= NE) return;
  int row = arows[e];
  int col = acols[e];
  float v = avals[e];
  if (lane < 24) {
    const float4* src = (const float4*)(ego + (size_t)col * DD);
    float4 x = src[lane];
    float* dst = side + (size_t)row * DD + lane * 4;
    unsafeAtomicAdd(dst + 0, v * x.x);
    unsafeAtomicAdd(dst + 1, v * x.y);
    unsafeAtomicAdd(dst + 2, v * x.z);
    unsafeAtomicAdd(dst + 3, v * x.w);
  }
}

__global__ __launch_bounds__(192) void fuse_fb_kernel(
    const float* __restrict__ ego, const float* __restrict__ side,
    const float* __restrict__ W1, const float* __restrict__ b1,
    const float* __restrict__ W2, const float* __restrict__ b2,
    float* __restrict__ out)
{
  __shared__ float W1t[DD * DD];
  __shared__ float W2t[DD * DD];
  __shared__ float b1s[DD], b2s[DD];
  __shared__ float xs[192], ys[192];
  int tid = threadIdx.x;
  for (int i = tid; i < DD * DD; i += 192) {
    int j = i / DD, k = i - j * DD;
    W1t[k * DD + j] = W1[i];
    W2t[k * DD + j] = W2[i];
  }
  if (tid < DD) { b1s[tid] = b1[tid]; b2s[tid] = b2[tid]; }
  __syncthreads();
  int nl = tid / DD, j = tid - nl * DD;
  for (int p = blockIdx.x; p < NN / 2; p += gridDim.x) {
    int base = p * 192;
    float e = ego[base + tid], s = side[base + tid];
    xs[tid] = e + s; ys[tid] = e * s;
    __syncthreads();
    float a1 = b1s[j], a2 = b2s[j];
    const float* xr = xs + nl * DD;
    const float* yr = ys + nl * DD;
#pragma unroll 16
    for (int k = 0; k < DD; ++k) {
      a1 += xr[k] * W1t[k * DD + j];
      a2 += yr[k] * W2t[k * DD + j];
    }
    float r = lrelu(a1) + lrelu(a2);
    __syncthreads();
    out[base + tid] = r;
  }
}

// ========== build: binA binning + W->bf16 + ego->int8(row-scale) ==========
#define NB_W   ((DD * DD) / 256)       // 36
#define NB_Q   ((NN + 63) / 64)        // 782 quant blocks (64 rows each)
#define EPT    (EPA / 256)             // 8 edges per thread in binA
__global__ __launch_bounds__(256) void build_kernel(
    const int* __restrict__ rows, const int* __restrict__ cols,
    const float* __restrict__ vals,
    int* __restrict__ bptr, int* __restrict__ ovcur,
    int2* __restrict__ ovbuf, int2* __restrict__ buckets,
    const float* __restrict__ W1, const float* __restrict__ W2,
    unsigned short* __restrict__ Wb1, unsigned short* __restrict__ Wb2,
    const float* __restrict__ ego, unsigned char* __restrict__ egoq)
{
  __shared__ unsigned sw0[EPA];
  __shared__ unsigned sw1[EPA];
  __shared__ unsigned char sbid[EPA];
  __shared__ int bcnt[256], bofs[256], gbase[256], stmp[256];

  int blk = blockIdx.x;
  int tid = threadIdx.x;

  if (blk >= NBA) {
    int b = blk - NBA;
    if (b < NB_W) {
      int i = b * 256 + tid;  // [0, 9216)
      Wb1[i] = f2bf(W1[i]);
      Wb2[i] = f2bf(W2[i]);
    } else {
      // int8 quantization: 64 rows/block, 4 threads/row (24 values each)
      int r_loc = tid >> 2, q = tid & 3;
      int row = (b - NB_W) * 64 + r_loc;
      if (row < NN) {
        float4 f[6];
        const float4* src = (const float4*)(ego + (size_t)row * DD + q * 24);
#pragma unroll
        for (int t = 0; t < 6; ++t) f[t] = src[t];
        float m = 0.f;
#pragma unroll
        for (int t = 0; t < 6; ++t) {
          m = fmaxf(m, fmaxf(fmaxf(fabsf(f[t].x), fabsf(f[t].y)),
                             fmaxf(fabsf(f[t].z), fabsf(f[t].w))));
        }
        m = fmaxf(m, __shfl_xor(m, 1, 64));
        m = fmaxf(m, __shfl_xor(m, 2, 64));
        m = fmaxf(m, 1e-20f);
        float inv = 127.0f / m;
        unsigned* dst = (unsigned*)(egoq + (size_t)row * QROW) + q * 6;
#pragma unroll
        for (int t = 0; t < 6; ++t) {
          int q0 = __float2int_rn(f[t].x * inv);
          int q1 = __float2int_rn(f[t].y * inv);
          int q2 = __float2int_rn(f[t].z * inv);
          int q3 = __float2int_rn(f[t].w * inv);
          dst[t] = (unsigned)(q0 & 255) | ((unsigned)(q1 & 255) << 8) |
                   ((unsigned)(q2 & 255) << 16) | ((unsigned)(q3 & 255) << 24);
        }
        if (q == 0) *(float*)(egoq + (size_t)row * QROW + DD) = m * (1.0f / 127.0f);
      }
    }
    return;
  }

  // ---- binA part ----
  int base = blk * EPA;
  int cnt_here = min(EPA, NE - base);

  bcnt[tid] = 0;
  __syncthreads();

  unsigned w0[EPT], w1[EPT];
  int bb[EPT], lp[EPT];
#pragma unroll
  for (int k = 0; k < EPT; ++k) {
    int i = tid + k * 256;
    bb[k] = -1;
    if (i < cnt_here) {
      int e = base + i;
      int r = rows[e], c = cols[e];
      float v = vals[e];
      int b = r >> 8;
      bb[k] = b;
      w0[k] = (unsigned)c | ((unsigned)(r & 255) << 16) | ((unsigned)b << 24);
      w1[k] = (unsigned)f2bf(v);
      lp[k] = atomicAdd(&bcnt[b], 1);
    }
  }
  __syncthreads();

  int v = bcnt[tid];
  stmp[tid] = v;
  __syncthreads();
  for (int off = 1; off < 256; off <<= 1) {
    int add = (tid >= off) ? stmp[tid - off] : 0;
    __syncthreads();
    stmp[tid] += add;
    __syncthreads();
  }
  bofs[tid] = stmp[tid] - v;  // exclusive
  gbase[tid] = (tid < NBK && v > 0) ? atomicAdd(&bptr[tid], v) : 0;
  __syncthreads();

#pragma unroll
  for (int k = 0; k < EPT; ++k) {
    if (bb[k] >= 0) {
      int s = bofs[bb[k]] + lp[k];
      sw0[s] = w0[k];
      sw1[s] = w1[k];
      sbid[s] = (unsigned char)bb[k];
    }
  }
  __syncthreads();

  for (int i = tid; i < cnt_here; i += 256) {
    int b = sbid[i];
    int off = i - bofs[b];
    int g = gbase[b] + off;
    int2 ent = make_int2((int)sw0[i], (int)sw1[i]);
    if (g < BCAP) {
      buckets[(size_t)b * BCAP + g] = ent;
    } else {
      int op = atomicAdd(ovcur, 1);
      if (op < OVCAP) ovbuf[op] = ent;
    }
  }
}

// ========== binB: LDS-staged bucket + counting sort -> cv + row_start ==========
__global__ __launch_bounds__(256) void binB_kernel(
    const int2* __restrict__ buckets, const int* __restrict__ bptr,
    const int* __restrict__ ovcur, const int2* __restrict__ ovbuf,
    unsigned* __restrict__ cv, int* __restrict__ row_start)
{
  __shared__ int2 sent[BCAP];
  __shared__ int rcnt[256], rofs[256], rcur[256], stmp[256], sexc[256];
  int b = blockIdx.x, tid = threadIdx.x;

  int bv = (tid < NBK) ? bptr[tid] : 0;
  stmp[tid] = bv;
  __syncthreads();
  for (int off = 1; off < 256; off <<= 1) {
    int add = (tid >= off) ? stmp[tid - off] : 0;
    __syncthreads();
    stmp[tid] += add;
    __syncthreads();
  }
  sexc[tid] = stmp[tid] - bv;
  __syncthreads();
  int cvb = sexc[b];
  int total = bptr[b];
  int nreg = min(total, BCAP);
  int nov = min(*ovcur, OVCAP);
  const int2* reg = buckets + (size_t)b * BCAP;

  rcnt[tid] = 0;
  for (int i = tid; i < nreg; i += 256) sent[i] = reg[i];
  __syncthreads();

  for (int i = tid; i < nreg; i += 256) {
    unsigned w0 = (unsigned)sent[i].x;
    atomicAdd(&rcnt[(w0 >> 16) & 255], 1);
  }
  for (int i = tid; i < nov; i += 256) {
    unsigned w0 = (unsigned)ovbuf[i].x;
    if ((w0 >> 24) == (unsigned)b) atomicAdd(&rcnt[(w0 >> 16) & 255], 1);
  }
  __syncthreads();

  int v = rcnt[tid];
  stmp[tid] = v;
  __syncthreads();
  for (int off = 1; off < 256; off <<= 1) {
    int add = (tid >= off) ? stmp[tid - off] : 0;
    __syncthreads();
    stmp[tid] += add;
    __syncthreads();
  }
  rofs[tid] = stmp[tid] - v;
  rcur[tid] = rofs[tid];
  int grow = b * 256 + tid;
  if (grow <= NN) row_start[grow] = cvb + rofs[tid];
  __syncthreads();

  for (int i = tid; i < nreg; i += 256) {
    unsigned w0 = (unsigned)sent[i].x;
    unsigned w1 = (unsigned)sent[i].y;
    int rl = (w0 >> 16) & 255;
    int p = atomicAdd(&rcur[rl], 1);
    cv[cvb + p] = (w0 & 0xFFFFu) | (w1 << 16);
  }
  for (int i = tid; i < nov; i += 256) {
    unsigned w0 = (unsigned)ovbuf[i].x;
    unsigned w1 = (unsigned)ovbuf[i].y;
    if ((w0 >> 24) == (unsigned)b) {
      int rl = (w0 >> 16) & 255;
      int p = atomicAdd(&rcur[rl], 1);
      cv[cvb + p] = (w0 & 0xFFFFu) | (w1 << 16);
    }
  }
}

// ====== agg: wave/row, quarter-wave gathers, 3-phase pipeline (R12-proven) ======
__global__ __launch_bounds__(256) void agg_kernel(
    const unsigned char* __restrict__ egoq, const int* __restrict__ row_start,
    const unsigned* __restrict__ cv, unsigned* __restrict__ sideb) {
  int wid = threadIdx.x >> 6, lane = threadIdx.x & 63;
  int row = blockIdx.x * 4 + wid;
  if (row >= NN) return;
  int s = row_start[row], e = row_start[row + 1];
  int q = lane >> 4, ql = lane & 15;
  bool act = ql < 12;
  int ql8 = ql * 8;

  float a[4][8];
#pragma unroll
  for (int d = 0; d < 4; ++d)
#pragma unroll
    for (int j = 0; j < 8; ++j) a[d][j] = 0.f;

  for (int base = s; base < e; base += 64) {
    int idx = base + lane;
    unsigned pk = 0;
    if (idx < e) pk = cv[idx];
    int n = min(64, e - base);
    for (int i = 0; i < n; i += 16) {
      // phase 1: broadcast 4 packed entries to this quarter
      unsigned p[4];
#pragma unroll
      for (int d = 0; d < 4; ++d) p[d] = __shfl(pk, i + 4 * d + q, 64);
      // phase 2: issue all loads (16 gathers in flight per wave)
      uint2 u[4];
      float sc[4];
#pragma unroll
      for (int d = 0; d < 4; ++d) {
        const char* rowp = (const char*)egoq + ((size_t)(p[d] & 0xFFFFu) << 7);
        if (act) {
          u[d] = *(const uint2*)(rowp + ql8);
          sc[d] = *(const float*)(rowp + DD);
        } else {
          u[d] = make_uint2(0u, 0u);
          sc[d] = 0.f;
        }
      }
      // phase 3: fma everything
#pragma unroll
      for (int d = 0; d < 4; ++d) {
        float vs = bfhi(p[d]) * sc[d];
        a[d][0] += vs * sb(u[d].x, 0);
        a[d][1] += vs * sb(u[d].x, 1);
        a[d][2] += vs * sb(u[d].x, 2);
        a[d][3] += vs * sb(u[d].x, 3);
        a[d][4] += vs * sb(u[d].y, 0);
        a[d][5] += vs * sb(u[d].y, 1);
        a[d][6] += vs * sb(u[d].y, 2);
        a[d][7] += vs * sb(u[d].y, 3);
      }
    }
  }

  float r[8];
#pragma unroll
  for (int j = 0; j < 8; ++j) {
    r[j] = (a[0][j] + a[1][j]) + (a[2][j] + a[3][j]);
    r[j] += __shfl_xor(r[j], 16, 64);
    r[j] += __shfl_xor(r[j], 32, 64);
  }
  if (q == 0 && act) {
    uint4 o;
    o.x = (unsigned)f2bf(r[0]) | ((unsigned)f2bf(r[1]) << 16);
    o.y = (unsigned)f2bf(r[2]) | ((unsigned)f2bf(r[3]) << 16);
    o.z = (unsigned)f2bf(r[4]) | ((unsigned)f2bf(r[5]) << 16);
    o.w = (unsigned)f2bf(r[6]) | ((unsigned)f2bf(r[7]) << 16);
    *(uint4*)(sideb + (size_t)row * 48 + ql * 4) = o;
  }
}

// ========== fuse4: bf16 MFMA, staged from egoq(int8)+sideb(bf16) ==========
__global__ __launch_bounds__(256) void fuse4_kernel(
    const unsigned char* __restrict__ egoq, const unsigned* __restrict__ sideb,
    const unsigned short* __restrict__ Wb1, const unsigned short* __restrict__ Wb2,
    const float* __restrict__ b1, const float* __restrict__ b2,
    float* __restrict__ out)
{
  __shared__ unsigned short xs[FN * XST];
  __shared__ unsigned short ys[FN * XST];
  int tid = threadIdx.x;
  int nbase = blockIdx.x * FN;

  // stage x=e+s, y=e*s as bf16; FN*24 dword units, 6 iters/thread
  for (int i = tid; i < FN * 24; i += 256) {
    int r = i / 24, u = i - r * 24;
    float e0 = 0.f, e1 = 0.f, e2 = 0.f, e3 = 0.f;
    float s0 = 0.f, s1 = 0.f, s2 = 0.f, s3 = 0.f;
    if (nbase + r < NN) {
      const char* rowp = (const char*)egoq + ((size_t)(nbase + r) << 7);
      float sc = *(const float*)(rowp + DD);
      unsigned uq = *(const unsigned*)(rowp + u * 4);
      e0 = sc * sb(uq, 0);
      e1 = sc * sb(uq, 1);
      e2 = sc * sb(uq, 2);
      e3 = sc * sb(uq, 3);
      uint2 sv = *(const uint2*)(sideb + (size_t)(nbase + r) * 48 + u * 2);
      s0 = bflo(sv.x); s1 = bfhi(sv.x);
      s2 = bflo(sv.y); s3 = bfhi(sv.y);
    }
    unsigned xlo = (unsigned)f2bf(e0 + s0) | ((unsigned)f2bf(e1 + s1) << 16);
    unsigned xhi = (unsigned)f2bf(e2 + s2) | ((unsigned)f2bf(e3 + s3) << 16);
    unsigned ylo = (unsigned)f2bf(e0 * s0) | ((unsigned)f2bf(e1 * s1) << 16);
    unsigned yhi = (unsigned)f2bf(e2 * s2) | ((unsigned)f2bf(e3 * s3) << 16);
    *(uint2*)(xs + r * XST + u * 4) = make_uint2(xlo, xhi);
    *(uint2*)(ys + r * XST + u * 4) = make_uint2(ylo, yhi);
  }
  __syncthreads();

  int w = tid >> 6, l = tid & 63;
  int lrow = l & 15, lk = l >> 4;

  f32x4 acc1[6], acc2[6];
#pragma unroll
  for (int t = 0; t < 6; ++t) {
    acc1[t] = (f32x4){0.f, 0.f, 0.f, 0.f};
    acc2[t] = (f32x4){0.f, 0.f, 0.f, 0.f};
  }

  const unsigned short* xrow = xs + (w * 16 + lrow) * XST + lk * 8;
  const unsigned short* yrow = ys + (w * 16 + lrow) * XST + lk * 8;

#pragma unroll
  for (int kk = 0; kk < 3; ++kk) {
    short8v ax = *(const short8v*)(xrow + kk * 32);
    short8v ay = *(const short8v*)(yrow + kk * 32);
    int kb = kk * 32 + lk * 8;
#pragma unroll
    for (int t = 0; t < 6; ++t) {
      int j = t * 16 + lrow;
      short8v bw1 = *(const short8v*)(Wb1 + j * DD + kb);
      short8v bw2 = *(const short8v*)(Wb2 + j * DD + kb);
      acc1[t] = __builtin_amdgcn_mfma_f32_16x16x32_bf16(ax, bw1, acc1[t], 0, 0, 0);
      acc2[t] = __builtin_amdgcn_mfma_f32_16x16x32_bf16(ay, bw2, acc2[t], 0, 0, 0);
    }
  }

  int node0 = nbase + w * 16 + lk * 4;
#pragma unroll
  for (int t = 0; t < 6; ++t) {
    int j = t * 16 + lrow;
    float bb1 = b1[j], bb2 = b2[j];
#pragma unroll
    for (int i = 0; i < 4; ++i) {
      int node = node0 + i;
      if (node < NN)
        out[(size_t)node * DD + j] = lrelu(acc1[t][i] + bb1) + lrelu(acc2[t][i] + bb2);
    }
  }
}

// ================= launch =================
extern "C" void kernel_launch(void* const* d_in, const int* in_sizes, int n_in,
                              void* d_out, int out_size, void* d_ws, size_t ws_size,
                              hipStream_t stream) {
  const float* ego   = (const float*)d_in[0];
  const float* avals = (const float*)d_in[1];
  const float* W1    = (const float*)d_in[2];
  const float* b1    = (const float*)d_in[3];
  const float* W2    = (const float*)d_in[4];
  const float* b2    = (const float*)d_in[5];
  const int* arows   = (const int*)d_in[6];
  const int* acols   = (const int*)d_in[7];
  float* out = (float*)d_out;

  size_t off = 0;
  auto bump = [&](size_t bytes) {
    size_t o = off;
    off += (bytes + 1023) & ~(size_t)1023;
    return o;
  };
  char* ws = (char*)d_ws;
  size_t o_rs    = bump((size_t)(NN + 1) * 4);
  size_t o_cv    = bump((size_t)NE * 4);
  size_t o_wb1   = bump((size_t)DD * DD * 2);
  size_t o_wb2   = bump((size_t)DD * DD * 2);
  size_t o_egoq  = bump((size_t)NN * QROW);       // 6.4 MB int8 rows w/ scale
  size_t o_bptr  = bump((size_t)(NBK + 1) * 4);   // bptr[NBK] + ovcur
  size_t o_ovbuf = bump((size_t)OVCAP * 8);
  size_t o_sideb = bump((size_t)NN * DD * 2);     // 9.6 MB; buckets alias here
  size_t need = off;
  static_assert((size_t)NBK * BCAP * 8 <= (size_t)NN * DD * 2, "buckets fit in sideb");

  if (ws_size >= need) {
    int*  rs    = (int*)(ws + o_rs);
    unsigned* cv = (unsigned*)(ws + o_cv);
    unsigned short* Wb1  = (unsigned short*)(ws + o_wb1);
    unsigned short* Wb2  = (unsigned short*)(ws + o_wb2);
    unsigned char* egoq  = (unsigned char*)(ws + o_egoq);
    int*  bptr  = (int*)(ws + o_bptr);
    int*  ovcur = bptr + NBK;
    int2* ovbuf = (int2*)(ws + o_ovbuf);
    unsigned* sideb = (unsigned*)(ws + o_sideb);
    int2* buckets = (int2*)(ws + o_sideb);

    hipMemsetAsync(bptr, 0, (size_t)(NBK + 1) * 4, stream);
    build_kernel<<<NBA + NB_W + NB_Q, 256, 0, stream>>>(
        arows, acols, avals, bptr, ovcur, ovbuf, buckets,
        W1, W2, Wb1, Wb2, ego, egoq);
    binB_kernel<<<NBK, 256, 0, stream>>>(buckets, bptr, ovcur, ovbuf, cv, rs);
    agg_kernel<<<(NN + 3) / 4, 256, 0, stream>>>(egoq, rs, cv, sideb);
    fuse4_kernel<<<(NN + FN - 1) / FN, 256, 0, stream>>>(
        egoq, sideb, Wb1, Wb2, b1, b2, out);
  } else {
    size_t side_bytes = (size_t)NN * DD * sizeof(float);
    float* side = (ws_size >= side_bytes) ? (float*)d_ws : out;
    hipMemsetAsync(side, 0, side_bytes, stream);
    long long nthreads = (long long)NE * 32;
    int blocks = (int)((nthreads + 255) / 256);
    scatter_kernel<<<blocks, 256, 0, stream>>>(ego, avals, arows, acols, side);
    fuse_fb_kernel<<<1024, 192, 0, stream>>>(ego, side, W1, b1, W2, b2, out);
  }
}